// Round 3
// baseline (191.668 us; speedup 1.0000x reference)
//
#include <hip/hip_runtime.h>
#include <math.h>

#define D 20
#define RPT 2  // rows per thread

// d_ws layout (32-bit word offsets):
//   [0..3]   two doubles: acc[0]=sum_h, acc[1]=sum_abs
//   [4]      unsigned completion counter
//   [8..407] M1t[400] : M1t[j*D+d] = sum_e W[e][d]*W_init[e][j]
//   [408..427] c[20]  : c[j] = sum_e b[e]*W_init[e][j] + 1
#define WS_CTR_OFF 4
#define WS_M1T_OFF 8
#define WS_C_OFF (WS_M1T_OFF + D * D)

// One tiny block: fold the first two linears into (M1t, c), zero acc + counter.
__global__ void prep_kernel(const float* __restrict__ W,
                            const float* __restrict__ b,
                            const float* __restrict__ Wi,
                            float* __restrict__ wsf) {
  int t = threadIdx.x;
  if (t < D * D) {
    int j = t / D, d = t % D;
    float acc = 0.f;
#pragma unroll
    for (int e = 0; e < D; ++e) acc = fmaf(W[e * D + d], Wi[e * D + j], acc);
    wsf[WS_M1T_OFF + t] = acc;
  } else if (t < D * D + D) {
    int j = t - D * D;
    float acc = 1.0f;
#pragma unroll
    for (int e = 0; e < D; ++e) acc = fmaf(b[e], Wi[e * D + j], acc);
    wsf[WS_C_OFF + j] = acc;
  } else if (t == D * D + D) {
    double* acc = (double*)wsf;
    acc[0] = 0.0;
    acc[1] = 0.0;
    ((unsigned*)wsf)[WS_CTR_OFF] = 0u;
  }
}

// Fused main kernel with UNIFORM control flow: every thread runs the full
// body (tail threads clamp to the last valid rows and zero their
// contribution with a branchless mask). Uniform CF lets the compiler
// scalarize all constant loads (M1t, c, W, b are wave-uniform addresses)
// into s_load -> SGPRs, so inner FMAs are v_fma_f32 v,v,s with no
// per-lane memory traffic for constants.
// Last block to finish also does the finalize (halving count + output).
__global__ __launch_bounds__(256, 4) void fused_kernel(
    const float* __restrict__ X,
    const float* __restrict__ W,
    const float* __restrict__ b,
    const float* __restrict__ M1t,
    const float* __restrict__ c,
    double* __restrict__ acc,
    unsigned* __restrict__ ctr,
    float* __restrict__ out,
    int nrows, int nblocks) {
  const int t = threadIdx.x;

  const long long row0 = ((long long)blockIdx.x * 256 + t) * RPT;
  const long long rmax = (long long)nrows - RPT;
  const float valid = (row0 <= rmax) ? 1.0f : 0.0f;  // v_cndmask, no CF
  const long long r0 = (row0 <= rmax) ? row0 : rmax;

  // 2 rows * 20 floats = 160 contiguous bytes, 16B-aligned -> 10 float4s.
  float xf[RPT * D];
  const float4* __restrict__ Xv = (const float4*)(X + r0 * D);
#pragma unroll
  for (int i = 0; i < (RPT * D) / 4; ++i) {
    float4 v = Xv[i];
    xf[4 * i + 0] = v.x;
    xf[4 * i + 1] = v.y;
    xf[4 * i + 2] = v.z;
    xf[4 * i + 3] = v.w;
  }

  // Stage 1: h2[r][j] = relu(sum_d xf[r][d] * M1t[j][d] + c[j]).
  float h2[RPT][D];
#pragma unroll
  for (int j = 0; j < D; ++j) {
    float a0 = c[j], a1 = a0;
#pragma unroll
    for (int d = 0; d < D; ++d) {
      const float m = M1t[j * D + d];  // uniform -> s_load/SGPR
      a0 = fmaf(xf[d], m, a0);
      a1 = fmaf(xf[D + d], m, a1);
    }
    h2[0][j] = fmaxf(a0, 0.f);
    h2[1][j] = fmaxf(a1, 0.f);
  }

  // Stage 2: h3[r][j2] = sum_j h2[r][j] * W[j2][j] + b[j2]; reduce on the fly.
  float rs = 0.f, ra = 0.f;
#pragma unroll
  for (int j2 = 0; j2 < D; ++j2) {
    float a0 = b[j2], a1 = a0;
#pragma unroll
    for (int j = 0; j < D; ++j) {
      const float w = W[j2 * D + j];  // uniform -> s_load/SGPR
      a0 = fmaf(h2[0][j], w, a0);
      a1 = fmaf(h2[1][j], w, a1);
    }
    rs += a0 + a1;
    ra += fabsf(a0) + fabsf(a1);
  }
  rs *= valid;
  ra *= valid;

  // Wave (64-lane) shuffle reduction, cross-wave via LDS, 1 fp64 atomic/block.
  __shared__ float sred[8];
  __shared__ unsigned s_ticket;
#pragma unroll
  for (int off = 32; off > 0; off >>= 1) {
    rs += __shfl_down(rs, off, 64);
    ra += __shfl_down(ra, off, 64);
  }
  const int wave = t >> 6, lane = t & 63;
  if (lane == 0) {
    sred[wave] = rs;
    sred[4 + wave] = ra;
  }
  __syncthreads();
  if (t == 0) {
    float s1 = sred[0] + sred[1] + sred[2] + sred[3];
    float s2 = sred[4] + sred[5] + sred[6] + sred[7];
    atomicAdd(&acc[0], (double)s1);
    atomicAdd(&acc[1], (double)s2);
    __threadfence();  // release: acc updates visible before ticket
    s_ticket = atomicAdd(ctr, 1u);
  }
  __syncthreads();

  // Last block to check in finalizes: count halvings of sum(|h|), write out.
  if (s_ticket == (unsigned)(nblocks - 1) && t == 0) {
    __threadfence();  // acquire
    double sh = atomicAdd(&acc[0], 0.0);  // device-scope atomic read
    double sa = atomicAdd(&acc[1], 0.0);
    int k = 0;
    while (sa > 1.0 && k < 1100) {
      sa *= 0.5;
      ++k;
    }
    out[0] = ldexpf((float)sh, -k);
  }
}

extern "C" void kernel_launch(void* const* d_in, const int* in_sizes, int n_in,
                              void* d_out, int out_size, void* d_ws, size_t ws_size,
                              hipStream_t stream) {
  const float* X = (const float*)d_in[0];
  const float* W = (const float*)d_in[1];
  const float* b = (const float*)d_in[2];
  const float* Wi = (const float*)d_in[3];
  float* out = (float*)d_out;
  float* wsf = (float*)d_ws;
  double* acc = (double*)d_ws;
  unsigned* ctr = ((unsigned*)d_ws) + WS_CTR_OFF;
  const float* M1t = wsf + WS_M1T_OFF;
  const float* c = wsf + WS_C_OFF;

  const int nrows = in_sizes[0] / D;  // 1,000,000

  hipLaunchKernelGGL(prep_kernel, dim3(1), dim3(512), 0, stream, W, b, Wi, wsf);

  const int nthreads = (nrows + RPT - 1) / RPT;
  const int nblocks = (nthreads + 255) / 256;
  hipLaunchKernelGGL(fused_kernel, dim3(nblocks), dim3(256), 0, stream,
                     X, W, b, M1t, c, acc, ctr, out, nrows, nblocks);
}

// Round 4
// 161.170 us; speedup vs baseline: 1.1892x; 1.1892x over previous
//
#include <hip/hip_runtime.h>
#include <math.h>

#define D 20
#define RPT 4  // rows per thread

// d_ws layout (32-bit word offsets):
//   [0..3]     two doubles: acc[0]=sum_h, acc[1]=sum_abs
//   [8..407]   M1tT[400] : M1tT[d*D+j] = sum_e W[e][d]*W_init[e][j]  (d-major!)
//   [408..427] c[20]     : c[j] = sum_e b[e]*W_init[e][j] + 1
#define WS_M1TT_OFF 8
#define WS_C_OFF (WS_M1TT_OFF + D * D)

// One tiny block: fold first two linears into (M1tT, c), zero accumulators.
__global__ void prep_kernel(const float* __restrict__ W,
                            const float* __restrict__ b,
                            const float* __restrict__ Wi,
                            float* __restrict__ wsf) {
  int t = threadIdx.x;
  if (t < D * D) {
    int d = t / D, j = t % D;  // store d-major: M1tT[d][j]
    float acc = 0.f;
#pragma unroll
    for (int e = 0; e < D; ++e) acc = fmaf(W[e * D + d], Wi[e * D + j], acc);
    wsf[WS_M1TT_OFF + t] = acc;
  } else if (t < D * D + D) {
    int j = t - D * D;
    float acc = 1.0f;
#pragma unroll
    for (int e = 0; e < D; ++e) acc = fmaf(b[e], Wi[e * D + j], acc);
    wsf[WS_C_OFF + j] = acc;
  } else if (t == D * D + D) {
    double* acc = (double*)wsf;
    acc[0] = 0.0;
    acc[1] = 0.0;
  }
}

// Fused main kernel, RPT=4, d-blocked stage 1.
// Constants live in LDS; every read is wave-uniform (same address across the
// wave -> hardware broadcast, zero bank conflicts), contiguous float4s so the
// compiler emits ds_read_b128. 16 FMAs per b128 read; LDS pipe and VALU pipe
// run concurrently. Live set: h2[4][20] + 4 float4 X regs + 1 float4 const
// ~ 110 VGPRs -> fits __launch_bounds__(256,4)'s 128-VGPR cap, no spills.
__global__ __launch_bounds__(256, 4) void fused_kernel(
    const float* __restrict__ X,
    const float* __restrict__ W,
    const float* __restrict__ b,
    const float* __restrict__ M1tT,
    const float* __restrict__ c,
    double* __restrict__ acc,
    int nrows) {
  __shared__ __align__(16) float sM[D * D];   // M1tT, d-major
  __shared__ __align__(16) float sW[D * D];   // W, row-major (contig in j)
  __shared__ __align__(16) float sc[D];
  __shared__ __align__(16) float sb[D];
  __shared__ float sred[8];

  const int t = threadIdx.x;
  for (int i = t; i < D * D; i += 256) {
    sM[i] = M1tT[i];
    sW[i] = W[i];
  }
  if (t < D) {
    sc[t] = c[t];
    sb[t] = b[t];
  }
  __syncthreads();

  const long long row0 = ((long long)blockIdx.x * 256 + t) * RPT;
  const long long rmax = (long long)nrows - RPT;
  const float valid = (row0 <= rmax) ? 1.0f : 0.0f;  // branchless tail mask
  const long long r0 = (row0 <= rmax) ? row0 : rmax;

  // X rows for this thread: RPT*D = 80 floats = 20 float4s, 16B-aligned.
  const float4* __restrict__ Xv = (const float4*)(X + r0 * D);

  // h2 init = c[j] (broadcast float4 reads).
  float h2[RPT][D];
  const float4* scv = (const float4*)sc;
#pragma unroll
  for (int jv = 0; jv < D / 4; ++jv) {
    float4 cv = scv[jv];
#pragma unroll
    for (int r = 0; r < RPT; ++r) {
      h2[r][4 * jv + 0] = cv.x;
      h2[r][4 * jv + 1] = cv.y;
      h2[r][4 * jv + 2] = cv.z;
      h2[r][4 * jv + 3] = cv.w;
    }
  }

  // Stage 1, d-blocked: for each block of 4 d's, stream one float4 of X per
  // row (prefetched one block ahead) and rank-1-update h2 from sM rows.
  float xr[RPT][4];
  {
    // prefetch d-block 0
    float4 v0 = Xv[0 * 5 + 0], v1 = Xv[1 * 5 + 0], v2 = Xv[2 * 5 + 0], v3 = Xv[3 * 5 + 0];
    xr[0][0] = v0.x; xr[0][1] = v0.y; xr[0][2] = v0.z; xr[0][3] = v0.w;
    xr[1][0] = v1.x; xr[1][1] = v1.y; xr[1][2] = v1.z; xr[1][3] = v1.w;
    xr[2][0] = v2.x; xr[2][1] = v2.y; xr[2][2] = v2.z; xr[2][3] = v2.w;
    xr[3][0] = v3.x; xr[3][1] = v3.y; xr[3][2] = v3.z; xr[3][3] = v3.w;
  }
#pragma unroll
  for (int db = 0; db < D / 4; ++db) {
    float xn[RPT][4];
    if (db + 1 < D / 4) {  // compile-time condition (unrolled)
#pragma unroll
      for (int r = 0; r < RPT; ++r) {
        float4 v = Xv[r * 5 + db + 1];
        xn[r][0] = v.x; xn[r][1] = v.y; xn[r][2] = v.z; xn[r][3] = v.w;
      }
    }
#pragma unroll
    for (int dd = 0; dd < 4; ++dd) {
      const int d = 4 * db + dd;
      const float4* mrow = (const float4*)&sM[d * D];  // wave-uniform
#pragma unroll
      for (int jv = 0; jv < D / 4; ++jv) {
        float4 m = mrow[jv];
#pragma unroll
        for (int r = 0; r < RPT; ++r) {
          h2[r][4 * jv + 0] = fmaf(xr[r][dd], m.x, h2[r][4 * jv + 0]);
          h2[r][4 * jv + 1] = fmaf(xr[r][dd], m.y, h2[r][4 * jv + 1]);
          h2[r][4 * jv + 2] = fmaf(xr[r][dd], m.z, h2[r][4 * jv + 2]);
          h2[r][4 * jv + 3] = fmaf(xr[r][dd], m.w, h2[r][4 * jv + 3]);
        }
      }
    }
    if (db + 1 < D / 4) {
#pragma unroll
      for (int r = 0; r < RPT; ++r)
#pragma unroll
        for (int k = 0; k < 4; ++k) xr[r][k] = xn[r][k];
    }
  }

  // ReLU
#pragma unroll
  for (int r = 0; r < RPT; ++r)
#pragma unroll
    for (int j = 0; j < D; ++j) h2[r][j] = fmaxf(h2[r][j], 0.f);

  // Stage 2: h3[r][j2] = sum_j h2[r][j]*W[j2][j] + b[j2]; reduce on the fly.
  float rs = 0.f, ra = 0.f;
#pragma unroll
  for (int j2 = 0; j2 < D; ++j2) {
    const float4* wrow = (const float4*)&sW[j2 * D];  // wave-uniform
    float a0 = sb[j2], a1 = a0, a2 = a0, a3 = a0;
#pragma unroll
    for (int jv = 0; jv < D / 4; ++jv) {
      float4 w = wrow[jv];
      a0 = fmaf(h2[0][4 * jv + 0], w.x, a0);
      a1 = fmaf(h2[1][4 * jv + 0], w.x, a1);
      a2 = fmaf(h2[2][4 * jv + 0], w.x, a2);
      a3 = fmaf(h2[3][4 * jv + 0], w.x, a3);
      a0 = fmaf(h2[0][4 * jv + 1], w.y, a0);
      a1 = fmaf(h2[1][4 * jv + 1], w.y, a1);
      a2 = fmaf(h2[2][4 * jv + 1], w.y, a2);
      a3 = fmaf(h2[3][4 * jv + 1], w.y, a3);
      a0 = fmaf(h2[0][4 * jv + 2], w.z, a0);
      a1 = fmaf(h2[1][4 * jv + 2], w.z, a1);
      a2 = fmaf(h2[2][4 * jv + 2], w.z, a2);
      a3 = fmaf(h2[3][4 * jv + 2], w.z, a3);
      a0 = fmaf(h2[0][4 * jv + 3], w.w, a0);
      a1 = fmaf(h2[1][4 * jv + 3], w.w, a1);
      a2 = fmaf(h2[2][4 * jv + 3], w.w, a2);
      a3 = fmaf(h2[3][4 * jv + 3], w.w, a3);
    }
    rs += (a0 + a1) + (a2 + a3);
    ra += (fabsf(a0) + fabsf(a1)) + (fabsf(a2) + fabsf(a3));
  }
  rs *= valid;
  ra *= valid;

  // Wave shuffle reduction -> cross-wave LDS -> one fp64 atomic per block.
#pragma unroll
  for (int off = 32; off > 0; off >>= 1) {
    rs += __shfl_down(rs, off, 64);
    ra += __shfl_down(ra, off, 64);
  }
  const int wave = t >> 6, lane = t & 63;
  if (lane == 0) {
    sred[wave] = rs;
    sred[4 + wave] = ra;
  }
  __syncthreads();
  if (t == 0) {
    float s1 = sred[0] + sred[1] + sred[2] + sred[3];
    float s2 = sred[4] + sred[5] + sred[6] + sred[7];
    atomicAdd(&acc[0], (double)s1);
    atomicAdd(&acc[1], (double)s2);
  }
}

// Single-thread finalize: count halvings of sum(|h|), scale sum(h) by 2^-k.
__global__ void fin_kernel(const double* __restrict__ acc, float* __restrict__ out) {
  double s = acc[1];
  int k = 0;
  while (s > 1.0 && k < 1100) {
    s *= 0.5;
    ++k;
  }
  out[0] = ldexpf((float)acc[0], -k);
}

extern "C" void kernel_launch(void* const* d_in, const int* in_sizes, int n_in,
                              void* d_out, int out_size, void* d_ws, size_t ws_size,
                              hipStream_t stream) {
  const float* X = (const float*)d_in[0];
  const float* W = (const float*)d_in[1];
  const float* b = (const float*)d_in[2];
  const float* Wi = (const float*)d_in[3];
  float* out = (float*)d_out;
  float* wsf = (float*)d_ws;
  double* acc = (double*)d_ws;
  const float* M1tT = wsf + WS_M1TT_OFF;
  const float* c = wsf + WS_C_OFF;

  const int nrows = in_sizes[0] / D;  // 1,000,000

  hipLaunchKernelGGL(prep_kernel, dim3(1), dim3(512), 0, stream, W, b, Wi, wsf);

  const int nthreads = (nrows + RPT - 1) / RPT;
  const int nblocks = (nthreads + 255) / 256;
  hipLaunchKernelGGL(fused_kernel, dim3(nblocks), dim3(256), 0, stream,
                     X, W, b, M1tT, c, acc, nrows);

  hipLaunchKernelGGL(fin_kernel, dim3(1), dim3(1), 0, stream, acc, out);
}